// Round 1
// baseline (397.466 us; speedup 1.0000x reference)
//
#include <hip/hip_runtime.h>
#include <hip/hip_bf16.h>

typedef __bf16 bf16_t;
typedef __bf16 bf16x4 __attribute__((ext_vector_type(4)));
typedef __bf16 bf16x8 __attribute__((ext_vector_type(8)));
typedef float f32x4 __attribute__((ext_vector_type(4)));

typedef const __attribute__((address_space(1))) void gvoid_t;
typedef __attribute__((address_space(3))) void lvoid_t;

#define MB (1UL<<20)

__device__ __forceinline__ void gload_lds16(const void* g, void* l) {
    __builtin_amdgcn_global_load_lds((gvoid_t*)g, (lvoid_t*)l, 16, 0, 0);
}

// ---------------- cast f32 -> bf16 (vectorized, 4 elems/thread) ----------------
__global__ __launch_bounds__(256) void cast_kernel(const float* __restrict__ in,
                                                   bf16_t* __restrict__ out, int n4) {
    int i = blockIdx.x * 256 + threadIdx.x;
    if (i < n4) {
        float4 f = ((const float4*)in)[i];
        bf16x4 o;
        o[0] = (bf16_t)f.x; o[1] = (bf16_t)f.y; o[2] = (bf16_t)f.z; o[3] = (bf16_t)f.w;
        ((bf16x4*)out)[i] = o;
    }
}

// ---------------- generic BT GEMM: C[i,j] = sum_k A[i,k]*B[j,k] ----------------
// 128x128 tile, BK=32, 256 threads = 4 waves (2x2 of 64x64), mfma 16x16x32 bf16.
template<int A_F32, int OUT_BF16, int HAS_BIAS, int RELU, int HAS_RES, int VT_OUT>
__global__ __launch_bounds__(256)
void gemm_bt(const void* __restrict__ Ap, int lda,
             const bf16_t* __restrict__ Bp, int ldb,
             const float* __restrict__ bias,
             const float* __restrict__ res, int ldres,
             void* __restrict__ Cp, int ldc,
             int K, int tilesN,
             long sAb, long sAh, long sBb, long sBh, long sCb, long sCh,
             int nH)
{
    __shared__ bf16_t sA[128 * 32];
    __shared__ bf16_t sB[128 * 32];

    const int z = blockIdx.y;
    const int bb = z / nH, hh = z % nH;
    const int tile = blockIdx.x;
    const int tm = tile / tilesN, tn = tile % tilesN;
    const int rowBase = tm * 128, colBase = tn * 128;
    const int t = threadIdx.x;
    const int wave = t >> 6, lane = t & 63;
    const int wr = (wave >> 1) * 64, wc = (wave & 1) * 64;

    const bf16_t* Bbase = Bp + (long)bb * sBb + (long)hh * sBh;

    f32x4 acc[4][4] = {};

    // staging map: round r, thread t -> tile elements [r*2048 + t*8, +8)
    const int e0 = t * 8;
    const int r0row = e0 >> 5, scol = e0 & 31;
    const int r1row = r0row + 64;

    for (int k0 = 0; k0 < K; k0 += 32) {
        if constexpr (A_F32) {
            const float* Af = (const float*)Ap + (long)bb * sAb + (long)hh * sAh;
            #pragma unroll
            for (int r = 0; r < 2; ++r) {
                const int row = r ? r1row : r0row;
                const float* src = Af + (long)(rowBase + row) * lda + k0 + scol;
                float4 f0 = *(const float4*)src;
                float4 f1 = *(const float4*)(src + 4);
                bf16x8 v;
                v[0] = (bf16_t)f0.x; v[1] = (bf16_t)f0.y; v[2] = (bf16_t)f0.z; v[3] = (bf16_t)f0.w;
                v[4] = (bf16_t)f1.x; v[5] = (bf16_t)f1.y; v[6] = (bf16_t)f1.z; v[7] = (bf16_t)f1.w;
                *(bf16x8*)&sA[r * 2048 + e0] = v;
            }
        } else {
            const bf16_t* Ab = (const bf16_t*)Ap + (long)bb * sAb + (long)hh * sAh;
            #pragma unroll
            for (int r = 0; r < 2; ++r) {
                const int row = r ? r1row : r0row;
                const bf16_t* src = Ab + (long)(rowBase + row) * lda + k0 + scol;
                char* dst = (char*)sA + r * 4096 + wave * 1024;  // wave-uniform base
                gload_lds16(src, dst);
            }
        }
        #pragma unroll
        for (int r = 0; r < 2; ++r) {
            const int row = r ? r1row : r0row;
            const bf16_t* src = Bbase + (long)(colBase + row) * ldb + k0 + scol;
            char* dst = (char*)sB + r * 4096 + wave * 1024;
            gload_lds16(src, dst);
        }
        asm volatile("s_waitcnt vmcnt(0)" ::: "memory");
        __syncthreads();

        const int kf = (lane >> 4) * 8;
        const int lr = lane & 15;
        bf16x8 af[4], bfr[4];
        #pragma unroll
        for (int m = 0; m < 4; ++m) af[m] = *(const bf16x8*)&sA[(wr + m * 16 + lr) * 32 + kf];
        #pragma unroll
        for (int n = 0; n < 4; ++n) bfr[n] = *(const bf16x8*)&sB[(wc + n * 16 + lr) * 32 + kf];
        #pragma unroll
        for (int m = 0; m < 4; ++m)
            #pragma unroll
            for (int n = 0; n < 4; ++n)
                acc[m][n] = __builtin_amdgcn_mfma_f32_16x16x32_bf16(af[m], bfr[n], acc[m][n], 0, 0, 0);
        __syncthreads();
    }

    // epilogue: C/D layout col=lane&15, row=(lane>>4)*4+reg
    const long cOff = (long)bb * sCb + (long)hh * sCh;
    #pragma unroll
    for (int m = 0; m < 4; ++m) {
        #pragma unroll
        for (int r = 0; r < 4; ++r) {
            const int i = rowBase + wr + m * 16 + (lane >> 4) * 4 + r;
            #pragma unroll
            for (int n = 0; n < 4; ++n) {
                const int j = colBase + wc + n * 16 + (lane & 15);
                float v = acc[m][n][r];
                if constexpr (HAS_BIAS) v += bias[j];
                if constexpr (RELU) v = fmaxf(v, 0.0f);
                if constexpr (HAS_RES) v += res[(long)i * ldres + j];
                if constexpr (VT_OUT) {
                    // V projection: write transposed per head: Vt[b][h][c][m]
                    const long o = (((long)(i >> 10) * 8 + (j >> 7)) * 128 + (j & 127)) * 1024 + (i & 1023);
                    ((bf16_t*)Cp)[o] = (bf16_t)v;
                } else if constexpr (OUT_BF16) {
                    ((bf16_t*)Cp)[cOff + (long)i * ldc + j] = (bf16_t)v;
                } else {
                    ((float*)Cp)[cOff + (long)i * ldc + j] = v;
                }
            }
        }
    }
}

// ---------------- masked/scaled softmax, in place over d_out attn region ----------------
// one wave per row of 1024; row index = (b*8+h)*1024 + n
__global__ __launch_bounds__(256)
void softmax_kernel(float* __restrict__ attn,
                    const float* __restrict__ factors,   // (B,N,M)
                    const float* __restrict__ weights,   // (B,M)
                    const int* __restrict__ mmask,       // (B,M)
                    const int* __restrict__ amask)       // (B,1,N,M)
{
    const int row = blockIdx.x * 4 + (threadIdx.x >> 6);
    const int lane = threadIdx.x & 63;
    const int n = row & 1023;
    const int b = row >> 13;  // 8*1024 rows per batch
    float* p = attn + (long)row * 1024;
    const float4* fac = (const float4*)(factors + ((long)b * 1024 + n) * 1024);
    const float4* wt  = (const float4*)(weights + (long)b * 1024);
    const int4*   mm  = (const int4*)(mmask + (long)b * 1024);
    const int4*   am  = (const int4*)(amask + ((long)b * 1024 + n) * 1024);
    const float scale = 0.08838834764831845f;  // 1/sqrt(128)
    const float NEGINF = -__builtin_inff();

    float vals[16];
    float mx = NEGINF;
    #pragma unroll
    for (int jj = 0; jj < 4; ++jj) {
        const int v4 = lane + jj * 64;
        float4 sc = ((const float4*)p)[v4];
        float4 fa = fac[v4];
        float4 w4 = wt[v4];
        int4 m4 = mm[v4];
        int4 a4 = am[v4];
        float s0 = sc.x * scale * fa.x * w4.x; if (m4.x | a4.x) s0 = NEGINF;
        float s1 = sc.y * scale * fa.y * w4.y; if (m4.y | a4.y) s1 = NEGINF;
        float s2 = sc.z * scale * fa.z * w4.z; if (m4.z | a4.z) s2 = NEGINF;
        float s3 = sc.w * scale * fa.w * w4.w; if (m4.w | a4.w) s3 = NEGINF;
        vals[jj * 4 + 0] = s0; vals[jj * 4 + 1] = s1;
        vals[jj * 4 + 2] = s2; vals[jj * 4 + 3] = s3;
        mx = fmaxf(mx, fmaxf(fmaxf(s0, s1), fmaxf(s2, s3)));
    }
    #pragma unroll
    for (int off = 32; off > 0; off >>= 1) mx = fmaxf(mx, __shfl_xor(mx, off));
    float sum = 0.f;
    #pragma unroll
    for (int q = 0; q < 16; ++q) { float e = __expf(vals[q] - mx); vals[q] = e; sum += e; }
    #pragma unroll
    for (int off = 32; off > 0; off >>= 1) sum += __shfl_xor(sum, off);
    const float inv = 1.0f / sum;
    #pragma unroll
    for (int jj = 0; jj < 4; ++jj) {
        const int v4 = lane + jj * 64;
        float4 o;
        o.x = vals[jj * 4 + 0] * inv; o.y = vals[jj * 4 + 1] * inv;
        o.z = vals[jj * 4 + 2] * inv; o.w = vals[jj * 4 + 3] * inv;
        ((float4*)p)[v4] = o;
    }
}

// ---------------- LayerNorm over rows of 1024, one wave per row ----------------
template<int WRITE_BF16>
__global__ __launch_bounds__(256)
void ln_kernel(const float* __restrict__ x,
               const float* __restrict__ g,
               const float* __restrict__ bt,
               float* __restrict__ outf,
               bf16_t* __restrict__ outb)
{
    const int row = blockIdx.x * 4 + (threadIdx.x >> 6);
    const int lane = threadIdx.x & 63;
    const float* p = x + (long)row * 1024;
    float v[16];
    float s = 0.f;
    #pragma unroll
    for (int jj = 0; jj < 4; ++jj) {
        float4 f = ((const float4*)p)[lane + jj * 64];
        v[jj * 4 + 0] = f.x; v[jj * 4 + 1] = f.y; v[jj * 4 + 2] = f.z; v[jj * 4 + 3] = f.w;
        s += f.x + f.y + f.z + f.w;
    }
    #pragma unroll
    for (int off = 32; off > 0; off >>= 1) s += __shfl_xor(s, off);
    const float mu = s * (1.0f / 1024.0f);
    float q = 0.f;
    #pragma unroll
    for (int i = 0; i < 16; ++i) { float d = v[i] - mu; q += d * d; }
    #pragma unroll
    for (int off = 32; off > 0; off >>= 1) q += __shfl_xor(q, off);
    const float rstd = rsqrtf(q * (1.0f / 1024.0f) + 1e-5f);
    #pragma unroll
    for (int jj = 0; jj < 4; ++jj) {
        const int v4 = lane + jj * 64;
        float4 gg = ((const float4*)g)[v4];
        float4 bb = ((const float4*)bt)[v4];
        float4 o;
        o.x = (v[jj * 4 + 0] - mu) * rstd * gg.x + bb.x;
        o.y = (v[jj * 4 + 1] - mu) * rstd * gg.y + bb.y;
        o.z = (v[jj * 4 + 2] - mu) * rstd * gg.z + bb.z;
        o.w = (v[jj * 4 + 3] - mu) * rstd * gg.w + bb.w;
        ((float4*)outf)[(long)row * 256 + v4] = o;
        if constexpr (WRITE_BF16) {
            bf16x4 ob;
            ob[0] = (bf16_t)o.x; ob[1] = (bf16_t)o.y; ob[2] = (bf16_t)o.z; ob[3] = (bf16_t)o.w;
            ((bf16x4*)outb)[(long)row * 256 + v4] = ob;
        }
    }
}

extern "C" void kernel_launch(void* const* d_in, const int* in_sizes, int n_in,
                              void* d_out, int out_size, void* d_ws, size_t ws_size,
                              hipStream_t stream)
{
    (void)in_sizes; (void)n_in; (void)out_size; (void)ws_size;
    const float* input_states     = (const float*)d_in[0];
    const float* memory_states    = (const float*)d_in[1];
    const float* memory_weights   = (const float*)d_in[2];
    const int*   memory_masks     = (const int*)d_in[3];
    const float* attention_factors= (const float*)d_in[4];
    const int*   attention_masks  = (const int*)d_in[5];
    const float* Wq = (const float*)d_in[6];
    const float* bq = (const float*)d_in[7];
    const float* Wk = (const float*)d_in[8];
    const float* bk = (const float*)d_in[9];
    const float* Wv = (const float*)d_in[10];
    const float* bv = (const float*)d_in[11];
    const float* Wo = (const float*)d_in[12];
    const float* bo = (const float*)d_in[13];
    const float* g1 = (const float*)d_in[14];
    const float* b1 = (const float*)d_in[15];
    const float* We = (const float*)d_in[16];
    const float* be = (const float*)d_in[17];
    const float* Ws = (const float*)d_in[18];
    const float* bs = (const float*)d_in[19];
    const float* g2 = (const float*)d_in[20];
    const float* b2 = (const float*)d_in[21];

    float* out0 = (float*)d_out;                         // (4,1024,1024)
    float* attn = (float*)d_out + 4L * 1024 * 1024;      // (4,8,1024,1024)

    char* ws = (char*)d_ws;
    bf16_t* Wqb  = (bf16_t*)(ws + 0 * MB);
    bf16_t* Wkb  = (bf16_t*)(ws + 2 * MB);
    bf16_t* Wvb  = (bf16_t*)(ws + 4 * MB);
    bf16_t* Wob  = (bf16_t*)(ws + 6 * MB);
    bf16_t* Web  = (bf16_t*)(ws + 8 * MB);
    bf16_t* Wsb  = (bf16_t*)(ws + 12 * MB);
    bf16_t* inb  = (bf16_t*)(ws + 16 * MB);
    bf16_t* memb = (bf16_t*)(ws + 24 * MB);
    bf16_t* Qb   = (bf16_t*)(ws + 32 * MB);
    bf16_t* Kb   = (bf16_t*)(ws + 40 * MB);
    bf16_t* Vtb  = (bf16_t*)(ws + 48 * MB);
    bf16_t* hidb = (bf16_t*)(ws + 56 * MB);
    float*  preLN= (float*)(ws + 64 * MB);
    float*  out1f= (float*)(ws + 80 * MB);
    bf16_t* out1b= (bf16_t*)(ws + 96 * MB);
    bf16_t* hffn = (bf16_t*)(ws + 104 * MB);

    auto cast = [&](const float* src, bf16_t* dst, long n) {
        cast_kernel<<<(int)(n / 4 / 256), 256, 0, stream>>>(src, dst, (int)(n / 4));
    };
    cast(Wq, Wqb, 1024L * 1024);
    cast(Wk, Wkb, 1024L * 1024);
    cast(Wv, Wvb, 1024L * 1024);
    cast(Wo, Wob, 1024L * 1024);
    cast(We, Web, 2048L * 1024);
    cast(Ws, Wsb, 1024L * 2048);
    cast(input_states, inb, 4096L * 1024);
    cast(memory_states, memb, 4096L * 1024);

    // Q = in @ Wq^T + bq (bf16 out)
    gemm_bt<0,1,1,0,0,0><<<dim3(256, 1), 256, 0, stream>>>(
        inb, 1024, Wqb, 1024, bq, nullptr, 0, Qb, 1024, 1024, 8, 0,0,0,0,0,0, 1);
    // K = mem @ Wk^T + bk
    gemm_bt<0,1,1,0,0,0><<<dim3(256, 1), 256, 0, stream>>>(
        memb, 1024, Wkb, 1024, bk, nullptr, 0, Kb, 1024, 1024, 8, 0,0,0,0,0,0, 1);
    // V = mem @ Wv^T + bv, written transposed per head Vt[b,h,c,m]
    gemm_bt<0,1,1,0,0,1><<<dim3(256, 1), 256, 0, stream>>>(
        memb, 1024, Wvb, 1024, bv, nullptr, 0, Vtb, 1024, 1024, 8, 0,0,0,0,0,0, 1);
    // scores[z=(b*8+h)] = Q_bh @ K_bh^T -> f32, straight into d_out attn region
    gemm_bt<0,0,0,0,0,0><<<dim3(64, 32), 256, 0, stream>>>(
        Qb, 1024, Kb, 1024, nullptr, nullptr, 0, attn, 1024, 128, 8,
        1048576L, 128L, 1048576L, 128L, 8388608L, 1048576L, 8);
    // masked scaled softmax in place
    softmax_kernel<<<8192, 256, 0, stream>>>(attn, attention_factors, memory_weights,
                                             memory_masks, attention_masks);
    // hidden = attn @ V  (A is f32 in d_out, reg-staged to bf16)
    gemm_bt<1,1,0,0,0,0><<<dim3(8, 32), 256, 0, stream>>>(
        attn, 1024, Vtb, 1024, nullptr, nullptr, 0, hidb, 1024, 1024, 1,
        8388608L, 1048576L, 1048576L, 131072L, 1048576L, 128L, 8);
    // preLN1 = hidden @ Wo^T + bo + input_states
    gemm_bt<0,0,1,0,1,0><<<dim3(256, 1), 256, 0, stream>>>(
        hidb, 1024, Wob, 1024, bo, input_states, 1024, preLN, 1024, 1024, 8, 0,0,0,0,0,0, 1);
    // out1 = LN(preLN1) -> f32 + bf16
    ln_kernel<1><<<1024, 256, 0, stream>>>(preLN, g1, b1, out1f, out1b);
    // h = relu(out1 @ We^T + be) -> bf16 (4096,2048)
    gemm_bt<0,1,1,1,0,0><<<dim3(512, 1), 256, 0, stream>>>(
        out1b, 1024, Web, 1024, be, nullptr, 0, hffn, 2048, 1024, 16, 0,0,0,0,0,0, 1);
    // preLN2 = h @ Ws^T + bs + out1
    gemm_bt<0,0,1,0,1,0><<<dim3(256, 1), 256, 0, stream>>>(
        hffn, 2048, Wsb, 2048, bs, out1f, 1024, preLN, 1024, 2048, 8, 0,0,0,0,0,0, 1);
    // out = LN(preLN2) -> d_out chunk 0
    ln_kernel<0><<<1024, 256, 0, stream>>>(preLN, g2, b2, out0, nullptr);
}